// Round 11
// baseline (52.632 us; speedup 1.0000x reference)
//
#include <hip/hip_runtime.h>

// softmax(ALPHA*|x-bins|) over K=32 bins + weighted-sum code.
// Memory-bound: ~286 MB traffic. Ladder: 65.3 -> 61.1 (DPP) -> 54.0us
// (raw v_exp, UNROLL=4) -> 51.5us (512-thread blocks; lifecycle overhead
// confirmed). Failed probes: UNROLL=8, 4-lane/8-bin, LDS transpose,
// persistent chunks, nontemporal (readback corruption).
// R10: 1024-thread blocks (4096 blocks, 64KiB contiguous each, 16 waves =
//      2 blocks/CU, still 32-wave packed). Per-thread structure identical.

#define SSQ_SCALE (-432.80854f)   // ALPHA * log2(e) = -300 * 1.4426950408889634
#define SSQ_UNROLL 4
#define SSQ_BLK 1024

typedef float f32x4 __attribute__((ext_vector_type(4)));

template <int CTRL>
__device__ __forceinline__ float dpp_f(float v) {
    int i = __builtin_bit_cast(int, v);
    i = __builtin_amdgcn_update_dpp(i, i, CTRL, 0xf, 0xf, true);
    return __builtin_bit_cast(float, i);
}
#define DPP_XOR1  0xB1   // quad_perm [1,0,3,2]
#define DPP_XOR2  0x4E   // quad_perm [2,3,0,1]
#define DPP_HMIRR 0x141  // row_half_mirror: lane i <-> 7-i within each 8

__device__ __forceinline__ float red8_min(float v) {
    v = fminf(v, dpp_f<DPP_XOR1>(v));   // GCNDPPCombine fuses mov+min
    v = fminf(v, dpp_f<DPP_XOR2>(v));
    v = fminf(v, dpp_f<DPP_HMIRR>(v));
    return v;
}
__device__ __forceinline__ float red8_sum(float v) {
    v += dpp_f<DPP_XOR1>(v);
    v += dpp_f<DPP_XOR2>(v);
    v += dpp_f<DPP_HMIRR>(v);
    return v;
}

__global__ __launch_bounds__(SSQ_BLK) void ssq_kernel(
    const float* __restrict__ x,      // n elements (B*L)
    const float* __restrict__ bins,   // K = 32
    float* __restrict__ soft,         // n*32 (viewed as n*8 float4s)
    float* __restrict__ code)         // n
{
    const int sub = threadIdx.x & 7;                 // which float4 of the 32 k's
    const f32x4 b4 = reinterpret_cast<const f32x4*>(bins)[sub];
    f32x4* __restrict__ soft4 = reinterpret_cast<f32x4*>(soft);

    const int base = blockIdx.x * (SSQ_BLK * SSQ_UNROLL) + threadIdx.x;

    // exact cover: grid*SSQ_BLK*UNROLL == n*8, no bounds checks anywhere.
    // all x loads issued before any compute (MLP; 8 lanes share each value)
    float xv[SSQ_UNROLL];
    #pragma unroll
    for (int u = 0; u < SSQ_UNROLL; ++u)
        xv[u] = x[(base + u * SSQ_BLK) >> 3];

    #pragma unroll
    for (int u = 0; u < SSQ_UNROLL; ++u) {
        const int f = base + u * SSQ_BLK;
        const float xu = xv[u];

        // signed diffs; abs folds into VOP3 input modifiers of min/fma
        const float t0 = xu - b4.x;
        const float t1 = xu - b4.y;
        const float t2 = xu - b4.z;
        const float t3 = xu - b4.w;

        // local min of |t| (v_min3 + abs mods), then 8-lane DPP butterfly
        const float dmin = red8_min(
            fminf(fminf(fabsf(t0), fabsf(t1)), fminf(fabsf(t2), fabsf(t3))));

        // e_k = 2^(SCALE*(|t_k| - dmin)); raw v_exp_f32, FTZ for far bins
        const float moff = -SSQ_SCALE * dmin;
        const float e0 = __builtin_amdgcn_exp2f(fmaf(SSQ_SCALE, fabsf(t0), moff));
        const float e1 = __builtin_amdgcn_exp2f(fmaf(SSQ_SCALE, fabsf(t1), moff));
        const float e2 = __builtin_amdgcn_exp2f(fmaf(SSQ_SCALE, fabsf(t2), moff));
        const float e3 = __builtin_amdgcn_exp2f(fmaf(SSQ_SCALE, fabsf(t3), moff));

        // joint reductions: denominator and weighted-bin numerator
        const float sum = red8_sum((e0 + e1) + (e2 + e3));
        const float num = red8_sum((e0 * b4.x + e1 * b4.y) +
                                   (e2 * b4.z + e3 * b4.w));

        const float inv = __builtin_amdgcn_rcpf(sum);
        f32x4 w;
        w.x = e0 * inv; w.y = e1 * inv; w.z = e2 * inv; w.w = e3 * inv;
        soft4[f] = w;                                // contiguous 1KiB/wave

        if (sub == 0) code[f >> 3] = num * inv;
    }
}

extern "C" void kernel_launch(void* const* d_in, const int* in_sizes, int n_in,
                              void* d_out, int out_size, void* d_ws, size_t ws_size,
                              hipStream_t stream) {
    const float* x    = (const float*)d_in[0];   // (B, L, 1) f32
    const float* bins = (const float*)d_in[1];   // (K,) f32, K == 32
    const int n = in_sizes[0];                   // B*L = 2,097,152

    float* soft = (float*)d_out;                 // (B, L, 32)
    float* code = soft + (size_t)n * 32;         // (B, L, 1)

    const int total_vec = n * 8;                 // 16,777,216 float4s
    const int grid = total_vec / (SSQ_BLK * SSQ_UNROLL);   // 4096, exact
    ssq_kernel<<<grid, SSQ_BLK, 0, stream>>>(x, bins, soft, code);
}

// Round 12
// 51.609 us; speedup vs baseline: 1.0198x; 1.0198x over previous
//
#include <hip/hip_runtime.h>

// softmax(ALPHA*|x-bins|) over K=32 bins + weighted-sum code.
// Memory-bound: ~286 MB traffic. Final ladder: 65.3 (shuffle) -> 61.1 (DPP)
// -> 54.0 (raw v_exp, no bounds checks) -> 51.5us (512-thread blocks)
// = 5.55 TB/s effective, 88% of the 6.3 TB/s mixed-stream copy ceiling.
// Block-size curve: 256t=54.0, 512t=51.5, 1024t=52.6 -> 512 is the peak.
// Probed and rejected: UNROLL=8 (57.1), 4-lane/8-bin (61.2), LDS transpose
// (80.5), persistent chunks (83.5), nontemporal (post-timing corruption).
// R11: restore the R9 best verbatim as the standing kernel.

#define SSQ_SCALE (-432.80854f)   // ALPHA * log2(e) = -300 * 1.4426950408889634
#define SSQ_UNROLL 4
#define SSQ_BLK 512

typedef float f32x4 __attribute__((ext_vector_type(4)));

template <int CTRL>
__device__ __forceinline__ float dpp_f(float v) {
    int i = __builtin_bit_cast(int, v);
    i = __builtin_amdgcn_update_dpp(i, i, CTRL, 0xf, 0xf, true);
    return __builtin_bit_cast(float, i);
}
#define DPP_XOR1  0xB1   // quad_perm [1,0,3,2]
#define DPP_XOR2  0x4E   // quad_perm [2,3,0,1]
#define DPP_HMIRR 0x141  // row_half_mirror: lane i <-> 7-i within each 8

__device__ __forceinline__ float red8_min(float v) {
    v = fminf(v, dpp_f<DPP_XOR1>(v));   // GCNDPPCombine fuses mov+min
    v = fminf(v, dpp_f<DPP_XOR2>(v));
    v = fminf(v, dpp_f<DPP_HMIRR>(v));
    return v;
}
__device__ __forceinline__ float red8_sum(float v) {
    v += dpp_f<DPP_XOR1>(v);
    v += dpp_f<DPP_XOR2>(v);
    v += dpp_f<DPP_HMIRR>(v);
    return v;
}

__global__ __launch_bounds__(SSQ_BLK) void ssq_kernel(
    const float* __restrict__ x,      // n elements (B*L)
    const float* __restrict__ bins,   // K = 32
    float* __restrict__ soft,         // n*32 (viewed as n*8 float4s)
    float* __restrict__ code)         // n
{
    const int sub = threadIdx.x & 7;                 // which float4 of the 32 k's
    const f32x4 b4 = reinterpret_cast<const f32x4*>(bins)[sub];
    f32x4* __restrict__ soft4 = reinterpret_cast<f32x4*>(soft);

    const int base = blockIdx.x * (SSQ_BLK * SSQ_UNROLL) + threadIdx.x;

    // exact cover: grid*SSQ_BLK*UNROLL == n*8, no bounds checks anywhere.
    // all x loads issued before any compute (MLP; 8 lanes share each value)
    float xv[SSQ_UNROLL];
    #pragma unroll
    for (int u = 0; u < SSQ_UNROLL; ++u)
        xv[u] = x[(base + u * SSQ_BLK) >> 3];

    #pragma unroll
    for (int u = 0; u < SSQ_UNROLL; ++u) {
        const int f = base + u * SSQ_BLK;
        const float xu = xv[u];

        // signed diffs; abs folds into VOP3 input modifiers of min/fma
        const float t0 = xu - b4.x;
        const float t1 = xu - b4.y;
        const float t2 = xu - b4.z;
        const float t3 = xu - b4.w;

        // local min of |t| (v_min3 + abs mods), then 8-lane DPP butterfly
        const float dmin = red8_min(
            fminf(fminf(fabsf(t0), fabsf(t1)), fminf(fabsf(t2), fabsf(t3))));

        // e_k = 2^(SCALE*(|t_k| - dmin)); raw v_exp_f32, FTZ for far bins
        const float moff = -SSQ_SCALE * dmin;
        const float e0 = __builtin_amdgcn_exp2f(fmaf(SSQ_SCALE, fabsf(t0), moff));
        const float e1 = __builtin_amdgcn_exp2f(fmaf(SSQ_SCALE, fabsf(t1), moff));
        const float e2 = __builtin_amdgcn_exp2f(fmaf(SSQ_SCALE, fabsf(t2), moff));
        const float e3 = __builtin_amdgcn_exp2f(fmaf(SSQ_SCALE, fabsf(t3), moff));

        // joint reductions: denominator and weighted-bin numerator
        const float sum = red8_sum((e0 + e1) + (e2 + e3));
        const float num = red8_sum((e0 * b4.x + e1 * b4.y) +
                                   (e2 * b4.z + e3 * b4.w));

        const float inv = __builtin_amdgcn_rcpf(sum);
        f32x4 w;
        w.x = e0 * inv; w.y = e1 * inv; w.z = e2 * inv; w.w = e3 * inv;
        soft4[f] = w;                                // contiguous 1KiB/wave

        if (sub == 0) code[f >> 3] = num * inv;
    }
}

extern "C" void kernel_launch(void* const* d_in, const int* in_sizes, int n_in,
                              void* d_out, int out_size, void* d_ws, size_t ws_size,
                              hipStream_t stream) {
    const float* x    = (const float*)d_in[0];   // (B, L, 1) f32
    const float* bins = (const float*)d_in[1];   // (K,) f32, K == 32
    const int n = in_sizes[0];                   // B*L = 2,097,152

    float* soft = (float*)d_out;                 // (B, L, 32)
    float* code = soft + (size_t)n * 32;         // (B, L, 1)

    const int total_vec = n * 8;                 // 16,777,216 float4s
    const int grid = total_vec / (SSQ_BLK * SSQ_UNROLL);   // 8192, exact
    ssq_kernel<<<grid, SSQ_BLK, 0, stream>>>(x, bins, soft, code);
}